// Round 22
// baseline (70.233 us; speedup 1.0000x reference)
//
#include <hip/hip_runtime.h>
#include <hip/hip_fp16.h>

#define B_   4
#define LQ_  256
#define LK_  512
#define DIN_ 512
#define H_   256
#define DV_  512

#define L2E 1.4426950408889634f   // log2(e)
// tanh(x) = 1 - 2/(e^{2x}+1);  e^{2(q+k)} = e^{2q} * e^{2k}.
// eq2/ek2 = 2^clamp(2x*L2E,±126): finite & nonzero -> no NaN; product
// over/underflow -> exact tanh saturation. Softmax without max-subtract is
// safe: |score| <= ~38, 512*e^38 << fp32 max (verified r17-r21).

// =====================================================================
// Kernel 1: proj PARTIAL GEMM — r15 tile body + r21 DYNAMIC QUEUE
// (512 persistent blocks, 640 tiles, dead K tiles skipped in-loop).
// =====================================================================
__global__ __launch_bounds__(256) void proj_partial_kernel(
    const float* __restrict__ Q, const float* __restrict__ K,
    const float* __restrict__ Wq, const float* __restrict__ Wk,
    const int* __restrict__ valid_lens, int* __restrict__ counter,
    float* __restrict__ qpart, float* __restrict__ ekTpart) {
  __shared__ float xs[64][68];
  __shared__ float ws[64][132];
  __shared__ int s_idx;

  const int t = threadIdx.x;
  const int hthr = t & 31;
  const int rthr = t >> 5;

  while (true) {
    __syncthreads();
    if (t == 0) s_idx = atomicAdd(counter, 1);
    __syncthreads();
    const int blk = s_idx;
    if (blk >= 640) break;

    const bool isQ = blk < 128;
    int b, row0, h0, ds;
    if (isQ) {
      ds = blk & 3; h0 = ((blk >> 2) & 1) * 128;
      const int rt = blk >> 3;
      b = rt >> 2; row0 = (rt & 3) * 64;
    } else {
      const int u = blk - 128;
      ds = u & 7; h0 = ((u >> 3) & 1) * 128;
      const int rt = u >> 4;             // batch-interleaved
      b = rt & 3; row0 = (rt >> 2) * 64;
      if (row0 >= valid_lens[b]) continue;   // dead tile: grab next
    }
    const int L = isQ ? LQ_ : LK_;
    const int dspan = isQ ? 128 : 64;
    const float* __restrict__ X  = (isQ ? Q : K) + ((size_t)(b * L + row0)) * DIN_ + ds * dspan;
    const float* __restrict__ Wb = (isQ ? Wq : Wk) + (size_t)(ds * dspan) * H_ + h0;

    float acc[8][4];
#pragma unroll
    for (int r = 0; r < 8; ++r)
#pragma unroll
      for (int c = 0; c < 4; ++c) acc[r][c] = 0.f;

    for (int dd = 0; dd < dspan; dd += 64) {
      __syncthreads();
#pragma unroll
      for (int u = 0; u < 4; ++u) {
        const int f = t + 256 * u;
        const int r = f >> 4, c4 = (f & 15) << 2;
        *(float4*)&xs[r][c4] = *(const float4*)&X[(size_t)r * DIN_ + dd + c4];
      }
#pragma unroll
      for (int u = 0; u < 8; ++u) {
        const int f = t + 256 * u;
        const int k = f >> 5, c4 = (f & 31) << 2;
        *(float4*)&ws[k][c4] = *(const float4*)&Wb[(size_t)(dd + k) * H_ + c4];
      }
      __syncthreads();

      for (int k = 0; k < 64; k += 8) {
        float4 w4[8];
#pragma unroll
        for (int k8 = 0; k8 < 8; ++k8)
          w4[k8] = *(const float4*)&ws[k + k8][4 * hthr];
#pragma unroll
        for (int rr = 0; rr < 8; ++rr) {
          const float4 xa = *(const float4*)&xs[rthr * 8 + rr][k];
          const float4 xb = *(const float4*)&xs[rthr * 8 + rr][k + 4];
          const float xv[8] = {xa.x, xa.y, xa.z, xa.w, xb.x, xb.y, xb.z, xb.w};
#pragma unroll
          for (int k8 = 0; k8 < 8; ++k8) {
            acc[rr][0] = fmaf(xv[k8], w4[k8].x, acc[rr][0]);
            acc[rr][1] = fmaf(xv[k8], w4[k8].y, acc[rr][1]);
            acc[rr][2] = fmaf(xv[k8], w4[k8].z, acc[rr][2]);
            acc[rr][3] = fmaf(xv[k8], w4[k8].w, acc[rr][3]);
          }
        }
      }
    }

    if (isQ) {
      float* dst = qpart + (size_t)ds * (B_ * LQ_ * H_);
#pragma unroll
      for (int rr = 0; rr < 8; ++rr) {
        const int row = row0 + rthr * 8 + rr;
        float4 o = {acc[rr][0], acc[rr][1], acc[rr][2], acc[rr][3]};
        *(float4*)&dst[(size_t)(b * LQ_ + row) * H_ + h0 + 4 * hthr] = o;
      }
    } else {
      float* dst = ekTpart + (size_t)ds * (B_ * H_ * LK_);
#pragma unroll
      for (int c = 0; c < 4; ++c) {
        const int h = h0 + 4 * hthr + c;
        float* p = &dst[((size_t)b * H_ + h) * LK_ + row0 + rthr * 8];
        float4 lo = {acc[0][c], acc[1][c], acc[2][c], acc[3][c]};
        float4 hi = {acc[4][c], acc[5][c], acc[6][c], acc[7][c]};
        *(float4*)p = lo;
        *(float4*)(p + 4) = hi;
      }
    }
  }
}

// =====================================================================
// Kernel 2: combine 8 ekT partials + squared exp  AND  V -> fp16.
// blocks [0,256): ek2 (+wsum in block 0); [256,768): Vh.
// =====================================================================
__global__ __launch_bounds__(512) void combine_kernel(
    const float* __restrict__ ekTpart, const float* __restrict__ V,
    const float* __restrict__ wv,
    float* __restrict__ ek2, __half* __restrict__ Vh, float* __restrict__ wsum) {
  const int blk = blockIdx.x;
  const int t = threadIdx.x;
  if (blk < 256) {
    const int k4 = blk * 512 + t;
    const size_t KN4 = (size_t)B_ * H_ * LK_ / 4;
    const float4* src = (const float4*)ekTpart;
    float4 s = src[k4];
#pragma unroll
    for (int p = 1; p < 8; ++p) {
      const float4 v = src[p * KN4 + k4];
      s.x += v.x; s.y += v.y; s.z += v.z; s.w += v.w;
    }
    float4 o;
    o.x = exp2f(fminf(fmaxf(s.x * (2.f * L2E), -126.f), 126.f));
    o.y = exp2f(fminf(fmaxf(s.y * (2.f * L2E), -126.f), 126.f));
    o.z = exp2f(fminf(fmaxf(s.z * (2.f * L2E), -126.f), 126.f));
    o.w = exp2f(fminf(fmaxf(s.w * (2.f * L2E), -126.f), 126.f));
    ((float4*)ek2)[k4] = o;
    if (blk == 0 && t < 64) {
      float sw = wv[t] + wv[t + 64] + wv[t + 128] + wv[t + 192];
#pragma unroll
      for (int off = 32; off; off >>= 1) sw += __shfl_xor(sw, off);
      if (t == 0) *wsum = sw;
    }
  } else {
    const int q4 = (blk - 256) * 512 + t;      // 262144 f4 of V
    const float4 v = ((const float4*)V)[q4];
    ((__half2*)Vh)[2 * q4]     = __floats2half2_rn(v.x, v.y);
    ((__half2*)Vh)[2 * q4 + 1] = __floats2half2_rn(v.z, v.w);
  }
}

// =====================================================================
// Kernel 3: FUSED eq+scores+softmax+AV — r17 STATIC structure (best
// measured) + SOFTWARE-PIPELINED loads (double-buffered kv / v regs:
// load group g+1 while computing group g -> per-wave latency hidden).
// block = (b, 2 q-rows), 512 thr, grid 512 (2/CU), batch-pair swizzle.
// vl-adaptive phase 1; softmax without max-subtract; fp16 V.
// =====================================================================
__global__ __launch_bounds__(512) void fused_attn_kernel(
    const float* __restrict__ qpart, const float* __restrict__ ek2,
    const __half* __restrict__ Vh, const float* __restrict__ wv,
    const float* __restrict__ wsum, const int* __restrict__ valid_lens,
    float* __restrict__ out) {
  __shared__ float eqs[2][260];
  __shared__ float wvs[256];
  __shared__ float ph[2][2][260];
  __shared__ float2 p2s[LK_];
  __shared__ float reds[8][2];

  const int blk = blockIdx.x;
  const int b  = (blk & 3) ^ ((blk >> 8) & 1);
  const int i0 = (blk >> 2) * 2;
  const int vl = valid_lens[b];
  const int t = threadIdx.x;
  const int lane = t & 63, wave = t >> 6;
  const float Wsum = *wsum;

  // ---- phase 0: eq2 rows (squared exp), wv stage ----
  const size_t QN = (size_t)B_ * LQ_ * H_;
  {
    const int r = t >> 8, h = t & 255;
    const size_t base = (size_t)(b * LQ_ + i0 + r) * H_ + h;
    const float v = qpart[base] + qpart[QN + base] +
                    qpart[2 * QN + base] + qpart[3 * QN + base];
    eqs[r][h] = exp2f(fminf(fmaxf(v * (2.f * L2E), -126.f), 126.f));
    if (r == 0) wvs[h] = wv[h];
  }
  __syncthreads();

  // macro: one 16-h compute group on kv[]
#define SCORE_GROUP(hbase)                                                  \
  {                                                                         \
    const int hX = (hbase);                                                 \
    _Pragma("unroll")                                                       \
    for (int g = 0; g < 4; ++g) {                                           \
      const float4 w4  = *(const float4*)&wvs[hX + 4 * g];                  \
      const float4 q0v = *(const float4*)&eqs[0][hX + 4 * g];               \
      const float4 q1v = *(const float4*)&eqs[1][hX + 4 * g];               \
      const float ww[4] = {w4.x, w4.y, w4.z, w4.w};                         \
      const float q0[4] = {q0v.x, q0v.y, q0v.z, q0v.w};                     \
      const float q1[4] = {q1v.x, q1v.y, q1v.z, q1v.w};                     \
      _Pragma("unroll")                                                     \
      for (int u = 0; u < 4; ++u) {                                         \
        const float k2 = kv[4 * g + u];                                     \
        a0 = fmaf(ww[u], __builtin_amdgcn_rcpf(fmaf(q0[u], k2, 1.f)), a0);  \
        a1 = fmaf(ww[u], __builtin_amdgcn_rcpf(fmaf(q1[u], k2, 1.f)), a1);  \
      }                                                                     \
    }                                                                       \
  }

  // ---- phase 1: scores (vl-adaptive), kv double-buffered ----
  const bool valid = t < vl;
  float s[2] = {-3.0e38f, -3.0e38f};
  if (vl > 256) {
    if (valid) {
      const float* __restrict__ kb = ek2 + (size_t)b * H_ * LK_ + t;
      float a0 = 0.f, a1 = 0.f;
      float kv[16], kvn[16];
#pragma unroll
      for (int u = 0; u < 16; ++u) kv[u] = kb[(size_t)u * LK_];
      for (int h = 0; h < H_; h += 16) {
        if (h + 16 < H_) {
#pragma unroll
          for (int u = 0; u < 16; ++u)
            kvn[u] = kb[(size_t)(h + 16 + u) * LK_];   // next group in flight
        }
        SCORE_GROUP(h);
#pragma unroll
        for (int u = 0; u < 16; ++u) kv[u] = kvn[u];
      }
      s[0] = fmaf(-2.f, a0, Wsum);
      s[1] = fmaf(-2.f, a1, Wsum);
    }
  } else {
    const int j = t & 255;
    const int hb = (t >> 8) * 128;
    if (j < vl) {
      const float* __restrict__ kb = ek2 + (size_t)b * H_ * LK_ + j;
      float a0 = 0.f, a1 = 0.f;
      float kv[16], kvn[16];
#pragma unroll
      for (int u = 0; u < 16; ++u) kv[u] = kb[(size_t)(hb + u) * LK_];
      for (int hh = 0; hh < 128; hh += 16) {
        if (hh + 16 < 128) {
#pragma unroll
          for (int u = 0; u < 16; ++u)
            kvn[u] = kb[(size_t)(hb + hh + 16 + u) * LK_];
        }
        SCORE_GROUP(hb + hh);
#pragma unroll
        for (int u = 0; u < 16; ++u) kv[u] = kvn[u];
      }
      ph[t >> 8][0][j] = a0;
      ph[t >> 8][1][j] = a1;
    }
    __syncthreads();
    if (valid) {
      s[0] = fmaf(-2.f, ph[0][0][t] + ph[1][0][t], Wsum);
      s[1] = fmaf(-2.f, ph[0][1][t] + ph[1][1][t], Wsum);
    }
  }
#undef SCORE_GROUP

  // ---- phase 2: softmax WITHOUT max-subtract ----
  float e[2], sum[2];
#pragma unroll
  for (int i = 0; i < 2; ++i) {
    e[i] = valid ? exp2f(s[i] * L2E) : 0.f;
    sum[i] = e[i];
  }
#pragma unroll
  for (int off = 32; off; off >>= 1)
#pragma unroll
    for (int i = 0; i < 2; ++i) sum[i] += __shfl_xor(sum[i], off);
  if (lane == 0)
#pragma unroll
    for (int i = 0; i < 2; ++i) reds[wave][i] = sum[i];
  __syncthreads();
  {
    float tot[2];
#pragma unroll
    for (int i = 0; i < 2; ++i) {
      tot[i] = reds[0][i];
#pragma unroll
      for (int w = 1; w < 8; ++w) tot[i] += reds[w][i];
    }
    float2 pv;
    pv.x = e[0] * __builtin_amdgcn_rcpf(tot[0]);
    pv.y = e[1] * __builtin_amdgcn_rcpf(tot[1]);
    p2s[t] = pv;
  }
  __syncthreads();

  // ---- phase 3: AV (thread = v-column), fp16 V, v double-buffered ----
  const __half* __restrict__ Vb = Vh + (size_t)b * LK_ * DV_ + t;
  float a0 = 0.f, a1 = 0.f;
  const int jv = vl & ~7;
  float v[8], vn[8];
  if (jv > 0) {
#pragma unroll
    for (int u = 0; u < 8; ++u) v[u] = __half2float(Vb[(size_t)u * DV_]);
  }
  for (int j = 0; j < jv; j += 8) {
    if (j + 8 < jv) {
#pragma unroll
      for (int u = 0; u < 8; ++u)
        vn[u] = __half2float(Vb[(size_t)(j + 8 + u) * DV_]);  // next in flight
    }
#pragma unroll
    for (int u = 0; u < 8; ++u) {
      const float2 pp = p2s[j + u];
      a0 = fmaf(pp.x, v[u], a0);
      a1 = fmaf(pp.y, v[u], a1);
    }
#pragma unroll
    for (int u = 0; u < 8; ++u) v[u] = vn[u];
  }
  for (int j = jv; j < vl; ++j) {
    const float vv = __half2float(Vb[(size_t)j * DV_]);
    const float2 pp = p2s[j];
    a0 = fmaf(pp.x, vv, a0);
    a1 = fmaf(pp.y, vv, a1);
  }
  out[(size_t)(b * LQ_ + i0) * DV_ + t]     = a0;
  out[(size_t)(b * LQ_ + i0 + 1) * DV_ + t] = a1;
}

extern "C" void kernel_launch(void* const* d_in, const int* in_sizes, int n_in,
                              void* d_out, int out_size, void* d_ws, size_t ws_size,
                              hipStream_t stream) {
  const float* queries    = (const float*)d_in[0];
  const float* keys       = (const float*)d_in[1];
  const float* values     = (const float*)d_in[2];
  const int*   valid_lens = (const int*)d_in[3];
  const float* Wq         = (const float*)d_in[4];
  const float* Wk         = (const float*)d_in[5];
  const float* wv         = (const float*)d_in[6];
  float* out = (float*)d_out;

  char* ws = (char*)d_ws;
  float*  qpart   = (float*)ws;                           // 4 x 1 MB @ 0
  float*  ekTpart = (float*)(ws + (size_t)( 4 << 20));    // 8 x 2 MB @ 4 MB
  float*  ek2     = (float*)(ws + (size_t)(20 << 20));    // 2 MB     @ 20 MB
  __half* Vh      = (__half*)(ws + (size_t)(22 << 20));   // 2 MB     @ 22 MB
  float*  wsum    = (float*)(ws + (size_t)(24 << 20));    // 4 B      @ 24 MB
  int*    counters= (int*)(ws + (size_t)(24 << 20) + 128);

  hipMemsetAsync(counters, 0, 2 * sizeof(int), stream);   // graph-safe node

  proj_partial_kernel<<<512, 256, 0, stream>>>(
      queries, keys, Wq, Wk, valid_lens, &counters[0], qpart, ekTpart);
  combine_kernel<<<768, 512, 0, stream>>>(
      ekTpart, values, wv, ek2, Vh, wsum);
  fused_attn_kernel<<<512, 512, 0, stream>>>(
      qpart, ek2, Vh, wv, wsum, valid_lens, out);
}

// Round 23
// 59.722 us; speedup vs baseline: 1.1760x; 1.1760x over previous
//
#include <hip/hip_runtime.h>
#include <hip/hip_fp16.h>

#define B_   4
#define LQ_  256
#define LK_  512
#define DIN_ 512
#define H_   256
#define DV_  512

#define L2E 1.4426950408889634f   // log2(e)
// tanh(x) = 1 - 2/(e^{2x}+1);  e^{2(q+k)} = e^{2q} * e^{2k}.
// eq2/ek2 = 2^clamp(2x*L2E,±126): finite & nonzero -> no NaN; product
// over/underflow -> exact tanh saturation. Softmax without max-subtract is
// safe: |score| <= ~38, 512*e^38 << fp32 max (verified r17-r22).

// =====================================================================
// Kernel 1: proj PARTIAL GEMM (r15/r17 static version — best measured).
// 64r x 128h tiles, 256 thr, micro 8r x 4h. d-split: Q=4, K=8.
// grid 640; dead K tiles exit.
// =====================================================================
__global__ __launch_bounds__(256) void proj_partial_kernel(
    const float* __restrict__ Q, const float* __restrict__ K,
    const float* __restrict__ Wq, const float* __restrict__ Wk,
    const int* __restrict__ valid_lens,
    float* __restrict__ qpart, float* __restrict__ ekTpart) {
  __shared__ float xs[64][68];
  __shared__ float ws[64][132];

  const int blk = blockIdx.x;
  const bool isQ = blk < 128;
  int b, row0, h0, ds;
  if (isQ) {
    ds = blk & 3; h0 = ((blk >> 2) & 1) * 128;
    const int rt = blk >> 3;
    b = rt >> 2; row0 = (rt & 3) * 64;
  } else {
    const int u = blk - 128;
    ds = u & 7; h0 = ((u >> 3) & 1) * 128;
    const int rt = u >> 4;             // batch-interleaved
    b = rt & 3; row0 = (rt >> 2) * 64;
    if (row0 >= valid_lens[b]) return;
  }
  const int L = isQ ? LQ_ : LK_;
  const int dspan = isQ ? 128 : 64;
  const float* __restrict__ X  = (isQ ? Q : K) + ((size_t)(b * L + row0)) * DIN_ + ds * dspan;
  const float* __restrict__ Wb = (isQ ? Wq : Wk) + (size_t)(ds * dspan) * H_ + h0;

  const int t = threadIdx.x;
  const int hthr = t & 31;
  const int rthr = t >> 5;

  float acc[8][4];
#pragma unroll
  for (int r = 0; r < 8; ++r)
#pragma unroll
    for (int c = 0; c < 4; ++c) acc[r][c] = 0.f;

  for (int dd = 0; dd < dspan; dd += 64) {
    __syncthreads();
#pragma unroll
    for (int u = 0; u < 4; ++u) {
      const int f = t + 256 * u;
      const int r = f >> 4, c4 = (f & 15) << 2;
      *(float4*)&xs[r][c4] = *(const float4*)&X[(size_t)r * DIN_ + dd + c4];
    }
#pragma unroll
    for (int u = 0; u < 8; ++u) {
      const int f = t + 256 * u;
      const int k = f >> 5, c4 = (f & 31) << 2;
      *(float4*)&ws[k][c4] = *(const float4*)&Wb[(size_t)(dd + k) * H_ + c4];
    }
    __syncthreads();

    for (int k = 0; k < 64; k += 8) {
      float4 w4[8];
#pragma unroll
      for (int k8 = 0; k8 < 8; ++k8)
        w4[k8] = *(const float4*)&ws[k + k8][4 * hthr];
#pragma unroll
      for (int rr = 0; rr < 8; ++rr) {
        const float4 xa = *(const float4*)&xs[rthr * 8 + rr][k];
        const float4 xb = *(const float4*)&xs[rthr * 8 + rr][k + 4];
        const float xv[8] = {xa.x, xa.y, xa.z, xa.w, xb.x, xb.y, xb.z, xb.w};
#pragma unroll
        for (int k8 = 0; k8 < 8; ++k8) {
          acc[rr][0] = fmaf(xv[k8], w4[k8].x, acc[rr][0]);
          acc[rr][1] = fmaf(xv[k8], w4[k8].y, acc[rr][1]);
          acc[rr][2] = fmaf(xv[k8], w4[k8].z, acc[rr][2]);
          acc[rr][3] = fmaf(xv[k8], w4[k8].w, acc[rr][3]);
        }
      }
    }
  }

  if (isQ) {
    float* dst = qpart + (size_t)ds * (B_ * LQ_ * H_);
#pragma unroll
    for (int rr = 0; rr < 8; ++rr) {
      const int row = row0 + rthr * 8 + rr;
      float4 o = {acc[rr][0], acc[rr][1], acc[rr][2], acc[rr][3]};
      *(float4*)&dst[(size_t)(b * LQ_ + row) * H_ + h0 + 4 * hthr] = o;
    }
  } else {
    float* dst = ekTpart + (size_t)ds * (B_ * H_ * LK_);
#pragma unroll
    for (int c = 0; c < 4; ++c) {
      const int h = h0 + 4 * hthr + c;
      float* p = &dst[((size_t)b * H_ + h) * LK_ + row0 + rthr * 8];
      float4 lo = {acc[0][c], acc[1][c], acc[2][c], acc[3][c]};
      float4 hi = {acc[4][c], acc[5][c], acc[6][c], acc[7][c]};
      *(float4*)p = lo;
      *(float4*)(p + 4) = hi;
    }
  }
}

// =====================================================================
// Kernel 2: combine 8 ekT partials + squared exp  AND  V -> fp16.
// blocks [0,256): ek2 (+wsum in block 0); [256,768): Vh. (r19/r20 ver.)
// =====================================================================
__global__ __launch_bounds__(512) void combine_kernel(
    const float* __restrict__ ekTpart, const float* __restrict__ V,
    const float* __restrict__ wv,
    float* __restrict__ ek2, __half* __restrict__ Vh, float* __restrict__ wsum) {
  const int blk = blockIdx.x;
  const int t = threadIdx.x;
  if (blk < 256) {
    const int k4 = blk * 512 + t;
    const size_t KN4 = (size_t)B_ * H_ * LK_ / 4;
    const float4* src = (const float4*)ekTpart;
    float4 s = src[k4];
#pragma unroll
    for (int p = 1; p < 8; ++p) {
      const float4 v = src[p * KN4 + k4];
      s.x += v.x; s.y += v.y; s.z += v.z; s.w += v.w;
    }
    float4 o;
    o.x = exp2f(fminf(fmaxf(s.x * (2.f * L2E), -126.f), 126.f));
    o.y = exp2f(fminf(fmaxf(s.y * (2.f * L2E), -126.f), 126.f));
    o.z = exp2f(fminf(fmaxf(s.z * (2.f * L2E), -126.f), 126.f));
    o.w = exp2f(fminf(fmaxf(s.w * (2.f * L2E), -126.f), 126.f));
    ((float4*)ek2)[k4] = o;
    if (blk == 0 && t < 64) {
      float sw = wv[t] + wv[t + 64] + wv[t + 128] + wv[t + 192];
#pragma unroll
      for (int off = 32; off; off >>= 1) sw += __shfl_xor(sw, off);
      if (t == 0) *wsum = sw;
    }
  } else {
    const int q4 = (blk - 256) * 512 + t;      // 262144 f4 of V
    const float4 v = ((const float4*)V)[q4];
    ((__half2*)Vh)[2 * q4]     = __floats2half2_rn(v.x, v.y);
    ((__half2*)Vh)[2 * q4 + 1] = __floats2half2_rn(v.z, v.w);
  }
}

// =====================================================================
// Kernel 3: FUSED eq+scores+softmax+AV — r17 static structure +
// kv double-buffer (phase 1) + fp16 V double-buffer (phase 3).
// block = (b, 2 q-rows), 512 thr, grid 512 (2/CU), batch-pair swizzle.
// vl-adaptive phase 1; softmax without max-subtract.
// =====================================================================
__global__ __launch_bounds__(512) void fused_attn_kernel(
    const float* __restrict__ qpart, const float* __restrict__ ek2,
    const __half* __restrict__ Vh, const float* __restrict__ wv,
    const float* __restrict__ wsum, const int* __restrict__ valid_lens,
    float* __restrict__ out) {
  __shared__ float eqs[2][260];
  __shared__ float wvs[256];
  __shared__ float ph[2][2][260];
  __shared__ float2 p2s[LK_];
  __shared__ float reds[8][2];

  const int blk = blockIdx.x;
  const int b  = (blk & 3) ^ ((blk >> 8) & 1);
  const int i0 = (blk >> 2) * 2;
  const int vl = valid_lens[b];
  const int t = threadIdx.x;
  const int lane = t & 63, wave = t >> 6;
  const float Wsum = *wsum;

  // ---- phase 0: eq2 rows (squared exp), wv stage ----
  const size_t QN = (size_t)B_ * LQ_ * H_;
  {
    const int r = t >> 8, h = t & 255;
    const size_t base = (size_t)(b * LQ_ + i0 + r) * H_ + h;
    const float v = qpart[base] + qpart[QN + base] +
                    qpart[2 * QN + base] + qpart[3 * QN + base];
    eqs[r][h] = exp2f(fminf(fmaxf(v * (2.f * L2E), -126.f), 126.f));
    if (r == 0) wvs[h] = wv[h];
  }
  __syncthreads();

#define SCORE_GROUP(hbase)                                                  \
  {                                                                         \
    const int hX = (hbase);                                                 \
    _Pragma("unroll")                                                       \
    for (int g = 0; g < 4; ++g) {                                           \
      const float4 w4  = *(const float4*)&wvs[hX + 4 * g];                  \
      const float4 q0v = *(const float4*)&eqs[0][hX + 4 * g];               \
      const float4 q1v = *(const float4*)&eqs[1][hX + 4 * g];               \
      const float ww[4] = {w4.x, w4.y, w4.z, w4.w};                         \
      const float q0[4] = {q0v.x, q0v.y, q0v.z, q0v.w};                     \
      const float q1[4] = {q1v.x, q1v.y, q1v.z, q1v.w};                     \
      _Pragma("unroll")                                                     \
      for (int u = 0; u < 4; ++u) {                                         \
        const float k2 = kv[4 * g + u];                                     \
        a0 = fmaf(ww[u], __builtin_amdgcn_rcpf(fmaf(q0[u], k2, 1.f)), a0);  \
        a1 = fmaf(ww[u], __builtin_amdgcn_rcpf(fmaf(q1[u], k2, 1.f)), a1);  \
      }                                                                     \
    }                                                                       \
  }

  // ---- phase 1: scores (vl-adaptive), kv double-buffered ----
  const bool valid = t < vl;
  float s[2] = {-3.0e38f, -3.0e38f};
  if (vl > 256) {
    if (valid) {
      const float* __restrict__ kb = ek2 + (size_t)b * H_ * LK_ + t;
      float a0 = 0.f, a1 = 0.f;
      float kv[16], kvn[16];
#pragma unroll
      for (int u = 0; u < 16; ++u) kv[u] = kb[(size_t)u * LK_];
      for (int h = 0; h < H_; h += 16) {
        if (h + 16 < H_) {
#pragma unroll
          for (int u = 0; u < 16; ++u)
            kvn[u] = kb[(size_t)(h + 16 + u) * LK_];   // next group in flight
        }
        SCORE_GROUP(h);
#pragma unroll
        for (int u = 0; u < 16; ++u) kv[u] = kvn[u];
      }
      s[0] = fmaf(-2.f, a0, Wsum);
      s[1] = fmaf(-2.f, a1, Wsum);
    }
  } else {
    const int j = t & 255;
    const int hb = (t >> 8) * 128;
    if (j < vl) {
      const float* __restrict__ kb = ek2 + (size_t)b * H_ * LK_ + j;
      float a0 = 0.f, a1 = 0.f;
      float kv[16], kvn[16];
#pragma unroll
      for (int u = 0; u < 16; ++u) kv[u] = kb[(size_t)(hb + u) * LK_];
      for (int hh = 0; hh < 128; hh += 16) {
        if (hh + 16 < 128) {
#pragma unroll
          for (int u = 0; u < 16; ++u)
            kvn[u] = kb[(size_t)(hb + hh + 16 + u) * LK_];
        }
        SCORE_GROUP(hb + hh);
#pragma unroll
        for (int u = 0; u < 16; ++u) kv[u] = kvn[u];
      }
      ph[t >> 8][0][j] = a0;
      ph[t >> 8][1][j] = a1;
    }
    __syncthreads();
    if (valid) {
      s[0] = fmaf(-2.f, ph[0][0][t] + ph[1][0][t], Wsum);
      s[1] = fmaf(-2.f, ph[0][1][t] + ph[1][1][t], Wsum);
    }
  }
#undef SCORE_GROUP

  // ---- phase 2: softmax WITHOUT max-subtract ----
  float e[2], sum[2];
#pragma unroll
  for (int i = 0; i < 2; ++i) {
    e[i] = valid ? exp2f(s[i] * L2E) : 0.f;
    sum[i] = e[i];
  }
#pragma unroll
  for (int off = 32; off; off >>= 1)
#pragma unroll
    for (int i = 0; i < 2; ++i) sum[i] += __shfl_xor(sum[i], off);
  if (lane == 0)
#pragma unroll
    for (int i = 0; i < 2; ++i) reds[wave][i] = sum[i];
  __syncthreads();
  {
    float tot[2];
#pragma unroll
    for (int i = 0; i < 2; ++i) {
      tot[i] = reds[0][i];
#pragma unroll
      for (int w = 1; w < 8; ++w) tot[i] += reds[w][i];
    }
    float2 pv;
    pv.x = e[0] * __builtin_amdgcn_rcpf(tot[0]);
    pv.y = e[1] * __builtin_amdgcn_rcpf(tot[1]);
    p2s[t] = pv;
  }
  __syncthreads();

  // ---- phase 3: AV (thread = v-column), fp16 V, double-buffered ----
  const __half* __restrict__ Vb = Vh + (size_t)b * LK_ * DV_ + t;
  float a0 = 0.f, a1 = 0.f;
  const int jv = vl & ~7;
  float v[8], vn[8];
  if (jv > 0) {
#pragma unroll
    for (int u = 0; u < 8; ++u) v[u] = __half2float(Vb[(size_t)u * DV_]);
  }
  for (int j = 0; j < jv; j += 8) {
    if (j + 8 < jv) {
#pragma unroll
      for (int u = 0; u < 8; ++u)
        vn[u] = __half2float(Vb[(size_t)(j + 8 + u) * DV_]);  // next in flight
    }
#pragma unroll
    for (int u = 0; u < 8; ++u) {
      const float2 pp = p2s[j + u];
      a0 = fmaf(pp.x, v[u], a0);
      a1 = fmaf(pp.y, v[u], a1);
    }
#pragma unroll
    for (int u = 0; u < 8; ++u) v[u] = vn[u];
  }
  for (int j = jv; j < vl; ++j) {
    const float vv = __half2float(Vb[(size_t)j * DV_]);
    const float2 pp = p2s[j];
    a0 = fmaf(pp.x, vv, a0);
    a1 = fmaf(pp.y, vv, a1);
  }
  out[(size_t)(b * LQ_ + i0) * DV_ + t]     = a0;
  out[(size_t)(b * LQ_ + i0 + 1) * DV_ + t] = a1;
}

extern "C" void kernel_launch(void* const* d_in, const int* in_sizes, int n_in,
                              void* d_out, int out_size, void* d_ws, size_t ws_size,
                              hipStream_t stream) {
  const float* queries    = (const float*)d_in[0];
  const float* keys       = (const float*)d_in[1];
  const float* values     = (const float*)d_in[2];
  const int*   valid_lens = (const int*)d_in[3];
  const float* Wq         = (const float*)d_in[4];
  const float* Wk         = (const float*)d_in[5];
  const float* wv         = (const float*)d_in[6];
  float* out = (float*)d_out;

  char* ws = (char*)d_ws;
  float*  qpart   = (float*)ws;                           // 4 x 1 MB @ 0
  float*  ekTpart = (float*)(ws + (size_t)( 4 << 20));    // 8 x 2 MB @ 4 MB
  float*  ek2     = (float*)(ws + (size_t)(20 << 20));    // 2 MB     @ 20 MB
  __half* Vh      = (__half*)(ws + (size_t)(22 << 20));   // 2 MB     @ 22 MB
  float*  wsum    = (float*)(ws + (size_t)(24 << 20));    // 4 B      @ 24 MB

  proj_partial_kernel<<<640, 256, 0, stream>>>(
      queries, keys, Wq, Wk, valid_lens, qpart, ekTpart);
  combine_kernel<<<768, 512, 0, stream>>>(
      ekTpart, values, wv, ek2, Vh, wsum);
  fused_attn_kernel<<<512, 512, 0, stream>>>(
      qpart, ek2, Vh, wv, wsum, valid_lens, out);
}